// Round 5
// baseline (309.755 us; speedup 1.0000x reference)
//
#include <hip/hip_runtime.h>
#include <stdint.h>

#define IN1 16
#define HIDC 10
#define OUT3 16
#define NTYPES 25
#define MAXB 32
#define HSTR 12   // padded row stride (floats) for h1/h2: 48B, 16B-aligned rows

// ---------------- zero two int regions ----------------
__global__ __launch_bounds__(256) void zero2_kernel(int* __restrict__ a, int na,
                                                    int* __restrict__ b, int nb) {
  int i = blockIdx.x * blockDim.x + threadIdx.x;
  int s = gridDim.x * blockDim.x;
  for (int j = i; j < na; j += s) a[j] = 0;
  for (int j = i; j < nb; j += s) b[j] = 0;
}

// ---------------- histogram + within-bucket rank (1 atomic per edge) ----------
__global__ __launch_bounds__(256) void hist_kernel(const int* __restrict__ edst,
                                                   int* __restrict__ deg,
                                                   int* __restrict__ pos, int E) {
  int e = blockIdx.x * blockDim.x + threadIdx.x;
  if (e < E) pos[e] = atomicAdd(&deg[edst[e]], 1);
}

// ---------------- hierarchical scan: A) per-1024-chunk local scan + chunk sum
__global__ __launch_bounds__(256) void scan_part_kernel(const int* __restrict__ deg,
                                                        int* __restrict__ row_ptr,
                                                        int* __restrict__ bsum, int N) {
  __shared__ int wsums[4];
  int tid = threadIdx.x, lane = tid & 63, wid = tid >> 6;
  int idx0 = (blockIdx.x * 256 + tid) * 4;      // 4 scalar elements per thread
  int4 v = make_int4(0, 0, 0, 0);
  if (idx0 < N)     v.x = deg[idx0];
  if (idx0 + 1 < N) v.y = deg[idx0 + 1];
  if (idx0 + 2 < N) v.z = deg[idx0 + 2];
  if (idx0 + 3 < N) v.w = deg[idx0 + 3];
  int s = v.x + v.y + v.z + v.w;
  int x = s;
  #pragma unroll
  for (int off = 1; off < 64; off <<= 1) {
    int y = __shfl_up(x, off);
    if (lane >= off) x += y;
  }
  if (lane == 63) wsums[wid] = x;
  __syncthreads();
  int wpre = 0;
  #pragma unroll
  for (int w = 0; w < 4; ++w) if (w < wid) wpre += wsums[w];
  int excl = x - s + wpre;                      // block-local exclusive prefix
  if (idx0 < N)     row_ptr[idx0]     = excl;
  if (idx0 + 1 < N) row_ptr[idx0 + 1] = excl + v.x;
  if (idx0 + 2 < N) row_ptr[idx0 + 2] = excl + v.x + v.y;
  if (idx0 + 3 < N) row_ptr[idx0 + 3] = excl + v.x + v.y + v.z;
  if (tid == 255) bsum[blockIdx.x] = excl + s;  // chunk total
}

// B) single-wave exclusive scan of chunk sums (G <= 64); writes row_ptr[N]=E
__global__ __launch_bounds__(64) void scan_bsum_kernel(int* __restrict__ bsum,
                                                       int* __restrict__ row_ptr,
                                                       int G, int N) {
  int tid = threadIdx.x;
  int v = (tid < G) ? bsum[tid] : 0;
  int x = v;
  #pragma unroll
  for (int off = 1; off < 64; off <<= 1) {
    int y = __shfl_up(x, off);
    if (tid >= off) x += y;
  }
  if (tid < G) bsum[tid] = x - v;               // exclusive chunk offsets
  if (tid == 63) row_ptr[N] = x;                // grand total
}

// C) add chunk offset to each local prefix
__global__ __launch_bounds__(256) void scan_add_kernel(int* __restrict__ row_ptr,
                                                       const int* __restrict__ bsum,
                                                       int N) {
  int i = blockIdx.x * blockDim.x + threadIdx.x;
  if (i < N) row_ptr[i] += bsum[i >> 10];
}

// ---------------- scatter edges into CSR order (plain stores) ----------------
__global__ __launch_bounds__(256) void permute_kernel(
    const int* __restrict__ edst, const int* __restrict__ esrc,
    const int* __restrict__ et, const float2* __restrict__ ef,
    const int* __restrict__ row_ptr, const int* __restrict__ pos,
    int4* __restrict__ edges, int E) {
  int e = blockIdx.x * blockDim.x + threadIdx.x;
  if (e >= E) return;
  int d = edst[e];
  int idx = row_ptr[d] + pos[e];
  float2 f = ef[e];
  int4 r;
  r.x = esrc[e];
  r.y = et[e];
  r.z = __float_as_int(f.x);
  r.w = __float_as_int(f.y);
  edges[idx] = r;
}

// ---------------- fused gather layer: msg-agg + mean + root + bias + relu -----
// R0 scheduling exactly (16 nodes/block, 16 lanes/node, churned grid, dynamic
// dispatch balancing).  Single-variable change vs R3: LDS traffic removed.
//  - wh/bh/wg/bg in per-lane registers (oc fixed per lane -> 6*IN_C regs)
//  - s_emb TRANSPOSED per type: [t][oc*ISTR + i], ISTR = IN_C padded to x4
//    -> per-edge emb row = 2-4 ds_read_b128 instead of IN_C strided b32
//  - x rows loaded as float4 into registers (XS = row stride in floats)
template<int IN_C, int O, int XS, bool POOL, int BS>
__global__ __launch_bounds__(BS) void layer_kernel(
    const float* __restrict__ xin,      // [N, XS]
    const int4* __restrict__ edges,     // CSR by dst: {src, type, f0, f1}
    const int* __restrict__ row_ptr,    // [N+1]
    const float* __restrict__ emb,      // [25, D]
    const float* __restrict__ wh, const float* __restrict__ bh,
    const float* __restrict__ wg, const float* __restrict__ bg,
    const float* __restrict__ root,     // [IN_C, O]
    const float* __restrict__ bias,     // [O]
    float* __restrict__ hout,           // [N, HSTR], or psum[B*16] if POOL
    const int* __restrict__ ctype, const int* __restrict__ bids,
    float* __restrict__ pcnt,           // [B] (POOL only)
    int N, int B)
{
  constexpr int D = IN_C * O;
  constexpr int ISTR = (IN_C + 3) & ~3;          // 16->16? pad +stagger below
  constexpr int ISTRP = (ISTR == IN_C) ? (ISTR + 4) : ISTR;  // ensure stagger
  constexpr int TSTR = O * ISTRP;                // floats per emb type row
  constexpr int NPB = BS / 16;                   // nodes per block
  __shared__ __align__(16) float s_emb[NTYPES * TSTR];
  __shared__ float s_root[D];
  __shared__ float s_bias[O];
  __shared__ float s_psum[POOL ? (MAXB * 16) : 1];
  __shared__ float s_pcnt[POOL ? MAXB : 1];

  int tid = threadIdx.x;
  // transpose-fill: s_emb[t][oc*ISTRP + i] = emb[t*D + i*O + oc]
  for (int k = tid; k < NTYPES * D; k += BS) {
    int t = k / D, r = k - t * D;
    int i = r / O, ocq = r - i * O;
    s_emb[t * TSTR + ocq * ISTRP + i] = emb[k];
  }
  for (int k = tid; k < D; k += BS) s_root[k] = root[k];
  if (tid < O) s_bias[tid] = bias[tid];
  if (POOL) {
    for (int i = tid; i < MAXB * 16; i += BS) s_psum[i] = 0.f;
    for (int i = tid; i < MAXB; i += BS) s_pcnt[i] = 0.f;
  }
  __syncthreads();

  int nl = tid >> 4;
  int o = tid & 15;
  int oc = (O == 16) ? o : ((o < O) ? o : 0);   // clamp idle lanes
  int n = blockIdx.x * NPB + nl;

  // per-lane coefficient registers (static indexing only)
  float cwh0[IN_C], cwh1[IN_C], cbh[IN_C], cwg0[IN_C], cwg1[IN_C], cbg[IN_C];
  #pragma unroll
  for (int i = 0; i < IN_C; ++i) {
    int k = i * O + oc;
    cwh0[i] = wh[k]; cwh1[i] = wh[D + k]; cbh[i] = bh[k];
    cwg0[i] = wg[k]; cwg1[i] = wg[D + k]; cbg[i] = bg[k];
  }

  float acc = 0.f;
  int start = 0, end = 0;
  if (n < N) { start = row_ptr[n]; end = row_ptr[n + 1]; }
  for (int e = start; e < end; ++e) {
    int4 r = edges[e];
    int src = r.x, t = r.y;
    float f0 = __int_as_float(r.z), f1 = __int_as_float(r.w);
    // x row -> regs (vectorized; XS keeps rows 16B-aligned)
    float xv[IN_C];
    const float* __restrict__ xr = xin + (size_t)src * XS;
    #pragma unroll
    for (int q = 0; q < IN_C / 4; ++q) {
      float4 v = ((const float4*)xr)[q];
      xv[4 * q + 0] = v.x; xv[4 * q + 1] = v.y;
      xv[4 * q + 2] = v.z; xv[4 * q + 3] = v.w;
    }
    if constexpr (IN_C % 4 == 2) {
      float2 v = ((const float2*)xr)[IN_C / 2 - 1];
      xv[IN_C - 2] = v.x; xv[IN_C - 1] = v.y;
    }
    // emb row for this lane's oc -> regs (b128 LDS reads)
    const float* __restrict__ er = s_emb + t * TSTR + oc * ISTRP;
    float ev[IN_C];
    #pragma unroll
    for (int q = 0; q < IN_C / 4; ++q) {
      float4 v = ((const float4*)er)[q];
      ev[4 * q + 0] = v.x; ev[4 * q + 1] = v.y;
      ev[4 * q + 2] = v.z; ev[4 * q + 3] = v.w;
    }
    if constexpr (IN_C % 4 == 2) {
      float2 v = ((const float2*)er)[IN_C / 2 - 1];
      ev[IN_C - 2] = v.x; ev[IN_C - 1] = v.y;
    }
    #pragma unroll
    for (int i = 0; i < IN_C; ++i) {
      float h = fmaf(f0, cwh0[i], fmaf(f1, cwh1[i], cbh[i]));
      float g = fmaf(f0, cwg0[i], fmaf(f1, cwg1[i], cbg[i]));
      float w = fmaxf(fmaf(ev[i], h, g), 0.f);
      acc = fmaf(xv[i], w, acc);
    }
  }

  if (n < N && o < O) {
    float inv = 1.0f / fmaxf((float)(end - start), 1.0f);
    float v = fmaf(acc, inv, s_bias[o]);
    const float* __restrict__ xr = xin + (size_t)n * XS;
    #pragma unroll
    for (int i = 0; i < IN_C; ++i) v = fmaf(xr[i], s_root[i * O + o], v);
    v = fmaxf(v, 0.f);
    if (!POOL) {
      hout[(size_t)n * HSTR + o] = v;
    } else {
      if (ctype[n] == 1) {
        int b = bids[n];
        atomicAdd(&s_psum[b * 16 + o], v);
        if (o == 0) atomicAdd(&s_pcnt[b], 1.0f);
      }
    }
  }

  if (POOL) {
    __syncthreads();
    for (int i = tid; i < B * 16; i += BS) {
      float v = s_psum[i];
      if (v != 0.f) atomicAdd(&hout[i], v);    // hout = psum (global)
    }
    for (int i = tid; i < B; i += BS) {
      float c = s_pcnt[i];
      if (c != 0.f) atomicAdd(&pcnt[i], c);
    }
  }
}

__global__ __launch_bounds__(256) void finalize_kernel(
    const float* __restrict__ psum, const float* __restrict__ pcnt,
    float* __restrict__ out, int B) {
  int i = blockIdx.x * blockDim.x + threadIdx.x;
  if (i >= B * OUT3) return;
  int b = i / OUT3;
  out[i] = psum[i] / fmaxf(pcnt[b], 1.0f);
}

// ---------------- launch ----------------
extern "C" void kernel_launch(void* const* d_in, const int* in_sizes, int n_in,
                              void* d_out, int out_size, void* d_ws, size_t ws_size,
                              hipStream_t stream)
{
  const float* x     = (const float*)d_in[0];
  const float* ef    = (const float*)d_in[1];
  const int*   et    = (const int*)d_in[2];
  const int*   esrc  = (const int*)d_in[3];
  const int*   edst  = (const int*)d_in[4];
  const int*   ctype = (const int*)d_in[5];
  const int*   bids  = (const int*)d_in[6];
  const float* emb1 = (const float*)d_in[8];
  const float* wh1  = (const float*)d_in[9];
  const float* bh1  = (const float*)d_in[10];
  const float* wg1  = (const float*)d_in[11];
  const float* bg1  = (const float*)d_in[12];
  const float* root1= (const float*)d_in[13];
  const float* bias1= (const float*)d_in[14];
  const float* emb2 = (const float*)d_in[15];
  const float* wh2  = (const float*)d_in[16];
  const float* bh2  = (const float*)d_in[17];
  const float* wg2  = (const float*)d_in[18];
  const float* bg2  = (const float*)d_in[19];
  const float* root2= (const float*)d_in[20];
  const float* bias2= (const float*)d_in[21];
  const float* emb3 = (const float*)d_in[22];
  const float* wh3  = (const float*)d_in[23];
  const float* bh3  = (const float*)d_in[24];
  const float* wg3  = (const float*)d_in[25];
  const float* bg3  = (const float*)d_in[26];
  const float* root3= (const float*)d_in[27];
  const float* bias3= (const float*)d_in[28];

  const int N = in_sizes[0] / IN1;
  const int E = in_sizes[2];
  const int B = out_size / OUT3;

  // workspace layout (16B-aligned sections)
  int4* edges   = (int4*)d_ws;                       // E recs (16B each)
  int*  deg     = (int*)(edges + E);                 // N
  int*  pos     = deg + N;                           // E
  int*  row_ptr = pos + E;                           // N+1
  int*  bsum    = row_ptr + (N + 1);                 // <=64 chunk sums
  float* h1     = (float*)(bsum + 64);               // N*HSTR (48B rows)
  float* h2     = h1 + (size_t)N * HSTR;             // N*HSTR
  float* psum   = h2 + (size_t)N * HSTR;             // B*16
  float* pcnt   = psum + (size_t)B * 16;             // B

  const int nChunk = (N + 1023) / 1024;              // 1024 deg entries per chunk

  zero2_kernel<<<128, 256, 0, stream>>>(deg, N, (int*)psum, B * 16 + B);
  hist_kernel<<<(E + 255) / 256, 256, 0, stream>>>(edst, deg, pos, E);
  scan_part_kernel<<<nChunk, 256, 0, stream>>>(deg, row_ptr, bsum, N);
  scan_bsum_kernel<<<1, 64, 0, stream>>>(bsum, row_ptr, nChunk, N);
  scan_add_kernel<<<(N + 255) / 256, 256, 0, stream>>>(row_ptr, bsum, N);
  permute_kernel<<<(E + 255) / 256, 256, 0, stream>>>(
      edst, esrc, et, (const float2*)ef, row_ptr, pos, edges, E);

  const int g256 = (N + 15) / 16;     // 16 nodes per 256-thread block
  layer_kernel<IN1, HIDC, IN1, false, 256><<<g256, 256, 0, stream>>>(
      x, edges, row_ptr, emb1, wh1, bh1, wg1, bg1, root1, bias1,
      h1, nullptr, nullptr, nullptr, N, B);
  layer_kernel<HIDC, HIDC, HSTR, false, 256><<<g256, 256, 0, stream>>>(
      h1, edges, row_ptr, emb2, wh2, bh2, wg2, bg2, root2, bias2,
      h2, nullptr, nullptr, nullptr, N, B);

  const int g1024 = (N + 63) / 64;    // 64 nodes per 1024-thread block
  layer_kernel<HIDC, OUT3, HSTR, true, 1024><<<g1024, 1024, 0, stream>>>(
      h2, edges, row_ptr, emb3, wh3, bh3, wg3, bg3, root3, bias3,
      psum, ctype, bids, pcnt, N, B);

  finalize_kernel<<<1, 256, 0, stream>>>(psum, pcnt, (float*)d_out, B);
}

// Round 7
// 251.153 us; speedup vs baseline: 1.2333x; 1.2333x over previous
//
#include <hip/hip_runtime.h>
#include <stdint.h>

#define IN1 16
#define HIDC 10
#define OUT3 16
#define NTYPES 25
#define MAXB 8
#define HSTR 12   // padded row stride (floats) for h1/h2: 48B, 16B-aligned rows

#define D1 (IN1 * HIDC)    // 160
#define D2 (HIDC * HIDC)   // 100
#define D3 (HIDC * OUT3)   // 160

// ---------------- zero two int regions ----------------
__global__ __launch_bounds__(256) void zero2_kernel(int* __restrict__ a, int na,
                                                    int* __restrict__ b, int nb) {
  int i = blockIdx.x * blockDim.x + threadIdx.x;
  int s = gridDim.x * blockDim.x;
  for (int j = i; j < na; j += s) a[j] = 0;
  for (int j = i; j < nb; j += s) b[j] = 0;
}

// ---------------- histogram + within-bucket rank (1 atomic per edge) ----------
__global__ __launch_bounds__(256) void hist_kernel(const int* __restrict__ edst,
                                                   int* __restrict__ deg,
                                                   int* __restrict__ pos, int E) {
  int e = blockIdx.x * blockDim.x + threadIdx.x;
  if (e < E) pos[e] = atomicAdd(&deg[edst[e]], 1);
}

// ---------------- hierarchical scan: A) per-1024-chunk local scan + chunk sum
__global__ __launch_bounds__(256) void scan_part_kernel(const int* __restrict__ deg,
                                                        int* __restrict__ row_ptr,
                                                        int* __restrict__ bsum, int N) {
  __shared__ int wsums[4];
  int tid = threadIdx.x, lane = tid & 63, wid = tid >> 6;
  int idx0 = (blockIdx.x * 256 + tid) * 4;      // 4 scalar elements per thread
  int4 v = make_int4(0, 0, 0, 0);
  if (idx0 < N)     v.x = deg[idx0];
  if (idx0 + 1 < N) v.y = deg[idx0 + 1];
  if (idx0 + 2 < N) v.z = deg[idx0 + 2];
  if (idx0 + 3 < N) v.w = deg[idx0 + 3];
  int s = v.x + v.y + v.z + v.w;
  int x = s;
  #pragma unroll
  for (int off = 1; off < 64; off <<= 1) {
    int y = __shfl_up(x, off);
    if (lane >= off) x += y;
  }
  if (lane == 63) wsums[wid] = x;
  __syncthreads();
  int wpre = 0;
  #pragma unroll
  for (int w = 0; w < 4; ++w) if (w < wid) wpre += wsums[w];
  int excl = x - s + wpre;                      // block-local exclusive prefix
  if (idx0 < N)     row_ptr[idx0]     = excl;
  if (idx0 + 1 < N) row_ptr[idx0 + 1] = excl + v.x;
  if (idx0 + 2 < N) row_ptr[idx0 + 2] = excl + v.x + v.y;
  if (idx0 + 3 < N) row_ptr[idx0 + 3] = excl + v.x + v.y + v.z;
  if (tid == 255) bsum[blockIdx.x] = excl + s;  // chunk total
}

// B) single-wave exclusive scan of chunk sums (G <= 64); writes row_ptr[N]=E
__global__ __launch_bounds__(64) void scan_bsum_kernel(int* __restrict__ bsum,
                                                       int* __restrict__ row_ptr,
                                                       int G, int N) {
  int tid = threadIdx.x;
  int v = (tid < G) ? bsum[tid] : 0;
  int x = v;
  #pragma unroll
  for (int off = 1; off < 64; off <<= 1) {
    int y = __shfl_up(x, off);
    if (tid >= off) x += y;
  }
  if (tid < G) bsum[tid] = x - v;               // exclusive chunk offsets
  if (tid == 63) row_ptr[N] = x;                // grand total
}

// C) add chunk offset to each local prefix
__global__ __launch_bounds__(256) void scan_add_kernel(int* __restrict__ row_ptr,
                                                       const int* __restrict__ bsum,
                                                       int N) {
  int i = blockIdx.x * blockDim.x + threadIdx.x;
  if (i < N) row_ptr[i] += bsum[i >> 10];
}

// ---------------- scatter edges into CSR order (plain stores) ----------------
__global__ __launch_bounds__(256) void permute_kernel(
    const int* __restrict__ edst, const int* __restrict__ esrc,
    const int* __restrict__ et, const float2* __restrict__ ef,
    const int* __restrict__ row_ptr, const int* __restrict__ pos,
    int4* __restrict__ edges, int E) {
  int e = blockIdx.x * blockDim.x + threadIdx.x;
  if (e >= E) return;
  int d = edst[e];
  int idx = row_ptr[d] + pos[e];
  float2 f = ef[e];
  int4 r;
  r.x = esrc[e];
  r.y = et[e];
  r.z = __float_as_int(f.x);
  r.w = __float_as_int(f.y);
  edges[idx] = r;
}

// ---------------- precompute packed P tables -----------------------------
// w_edge = relu(emb*(f0*wh0+f1*wh1+bh) + (f0*wg0+f1*wg1+bg))
//        = relu(f0*P0 + f1*P1 + P2)
// P0 = emb*wh0+wg0, P1 = emb*wh1+wg1, P2 = emb*bh+bg  (per type t, per k)
__global__ __launch_bounds__(256) void prep_kernel(
    const float* __restrict__ emb1, const float* __restrict__ wh1,
    const float* __restrict__ bh1, const float* __restrict__ wg1,
    const float* __restrict__ bg1,
    const float* __restrict__ emb2, const float* __restrict__ wh2,
    const float* __restrict__ bh2, const float* __restrict__ wg2,
    const float* __restrict__ bg2,
    const float* __restrict__ emb3, const float* __restrict__ wh3,
    const float* __restrict__ bh3, const float* __restrict__ wg3,
    const float* __restrict__ bg3,
    float4* __restrict__ P1, float4* __restrict__ P2, float4* __restrict__ P3)
{
  int i = blockIdx.x * 256 + threadIdx.x;
  const float *emb, *wh, *bh, *wg, *bg;
  float4* P; int D, k;
  if (i < NTYPES * D1) {
    emb = emb1; wh = wh1; bh = bh1; wg = wg1; bg = bg1; P = P1; D = D1; k = i;
  } else if (i < NTYPES * (D1 + D2)) {
    emb = emb2; wh = wh2; bh = bh2; wg = wg2; bg = bg2; P = P2; D = D2;
    k = i - NTYPES * D1;
  } else if (i < NTYPES * (D1 + D2 + D3)) {
    emb = emb3; wh = wh3; bh = bh3; wg = wg3; bg = bg3; P = P3; D = D3;
    k = i - NTYPES * (D1 + D2);
  } else return;
  int j = k - (k / D) * D;            // position within type row
  float e = emb[k];
  float4 p;
  p.x = fmaf(e, wh[j],     wg[j]);
  p.y = fmaf(e, wh[D + j], wg[D + j]);
  p.z = fmaf(e, bh[j],     bg[j]);
  p.w = 0.f;
  P[k] = p;
}

// ---------------- fused gather layer: msg-agg + mean + root + bias + relu ----
// R0 scheduling (16 lanes/node, churned grid, dynamic balancing).  Inner loop
// uses precomputed packed P: per (i,oc) = 1 broadcast ds_read_b128 + 4 VALU.
// Lane-adjacent oc -> contiguous float4 reads, conflict-free.  Tiny register
// footprint (no per-lane coefficient arrays -> no spill).
template<int IN_C, int O, int XS, bool POOL, int BS>
__global__ __launch_bounds__(BS) void layer_kernel(
    const float* __restrict__ xin,      // [N, XS]
    const int4* __restrict__ edges,     // CSR by dst: {src, type, f0, f1}
    const int* __restrict__ row_ptr,    // [N+1]
    const float4* __restrict__ Pg,      // [25*D] packed {P0,P1,P2,-}
    const float* __restrict__ root,     // [IN_C, O]
    const float* __restrict__ bias,     // [O]
    float* __restrict__ hout,           // [N, HSTR], or psum[B*16] if POOL
    const int* __restrict__ ctype, const int* __restrict__ bids,
    float* __restrict__ pcnt,           // [B] (POOL only)
    int N, int B)
{
  constexpr int D = IN_C * O;
  constexpr int NPB = BS / 16;          // nodes per block
  __shared__ float4 s_P[NTYPES * D];    // 40-62.5 KB
  __shared__ float s_psum[POOL ? (MAXB * 16) : 1];
  __shared__ float s_pcnt[POOL ? MAXB : 1];

  int tid = threadIdx.x;
  for (int k = tid; k < NTYPES * D; k += BS) s_P[k] = Pg[k];
  if (POOL) {
    for (int i = tid; i < MAXB * 16; i += BS) s_psum[i] = 0.f;
    for (int i = tid; i < MAXB; i += BS) s_pcnt[i] = 0.f;
  }
  __syncthreads();

  int nl = tid >> 4;
  int o = tid & 15;
  int oc = (O == 16) ? o : ((o < O) ? o : 0);   // clamp idle lanes
  int n = blockIdx.x * NPB + nl;

  float acc = 0.f;
  int start = 0, end = 0;
  if (n < N) { start = row_ptr[n]; end = row_ptr[n + 1]; }
  for (int e = start; e < end; ++e) {
    int4 r = edges[e];
    float f0 = __int_as_float(r.z), f1 = __int_as_float(r.w);
    const float4* __restrict__ pb = s_P + r.y * D + oc;   // stride O per i
    const float* __restrict__ xr = xin + (size_t)r.x * XS;
    #pragma unroll
    for (int q = 0; q < IN_C / 4; ++q) {
      float4 xq = ((const float4*)xr)[q];
      float4 p0 = pb[(4 * q + 0) * O];
      float4 p1 = pb[(4 * q + 1) * O];
      float4 p2 = pb[(4 * q + 2) * O];
      float4 p3 = pb[(4 * q + 3) * O];
      acc = fmaf(xq.x, fmaxf(fmaf(f0, p0.x, fmaf(f1, p0.y, p0.z)), 0.f), acc);
      acc = fmaf(xq.y, fmaxf(fmaf(f0, p1.x, fmaf(f1, p1.y, p1.z)), 0.f), acc);
      acc = fmaf(xq.z, fmaxf(fmaf(f0, p2.x, fmaf(f1, p2.y, p2.z)), 0.f), acc);
      acc = fmaf(xq.w, fmaxf(fmaf(f0, p3.x, fmaf(f1, p3.y, p3.z)), 0.f), acc);
    }
    if constexpr (IN_C % 4 == 2) {
      float2 xq = ((const float2*)xr)[IN_C / 2 - 1];
      float4 p0 = pb[(IN_C - 2) * O];
      float4 p1 = pb[(IN_C - 1) * O];
      acc = fmaf(xq.x, fmaxf(fmaf(f0, p0.x, fmaf(f1, p0.y, p0.z)), 0.f), acc);
      acc = fmaf(xq.y, fmaxf(fmaf(f0, p1.x, fmaf(f1, p1.y, p1.z)), 0.f), acc);
    }
  }

  if (n < N && o < O) {
    float inv = 1.0f / fmaxf((float)(end - start), 1.0f);
    float v = fmaf(acc, inv, bias[o]);
    const float* __restrict__ xr = xin + (size_t)n * XS;
    #pragma unroll
    for (int i = 0; i < IN_C; ++i) v = fmaf(xr[i], root[i * O + o], v);
    v = fmaxf(v, 0.f);
    if (!POOL) {
      hout[(size_t)n * HSTR + o] = v;
    } else {
      if (ctype[n] == 1) {
        int b = bids[n];
        atomicAdd(&s_psum[b * 16 + o], v);
        if (o == 0) atomicAdd(&s_pcnt[b], 1.0f);
      }
    }
  }

  if (POOL) {
    __syncthreads();
    for (int i = tid; i < B * 16; i += BS) {
      float v = s_psum[i];
      if (v != 0.f) atomicAdd(&hout[i], v);    // hout = psum (global)
    }
    for (int i = tid; i < B; i += BS) {
      float c = s_pcnt[i];
      if (c != 0.f) atomicAdd(&pcnt[i], c);
    }
  }
}

__global__ __launch_bounds__(256) void finalize_kernel(
    const float* __restrict__ psum, const float* __restrict__ pcnt,
    float* __restrict__ out, int B) {
  int i = blockIdx.x * blockDim.x + threadIdx.x;
  if (i >= B * OUT3) return;
  int b = i / OUT3;
  out[i] = psum[i] / fmaxf(pcnt[b], 1.0f);
}

// ---------------- launch ----------------
extern "C" void kernel_launch(void* const* d_in, const int* in_sizes, int n_in,
                              void* d_out, int out_size, void* d_ws, size_t ws_size,
                              hipStream_t stream)
{
  const float* x     = (const float*)d_in[0];
  const float* ef    = (const float*)d_in[1];
  const int*   et    = (const int*)d_in[2];
  const int*   esrc  = (const int*)d_in[3];
  const int*   edst  = (const int*)d_in[4];
  const int*   ctype = (const int*)d_in[5];
  const int*   bids  = (const int*)d_in[6];
  const float* emb1 = (const float*)d_in[8];
  const float* wh1  = (const float*)d_in[9];
  const float* bh1  = (const float*)d_in[10];
  const float* wg1  = (const float*)d_in[11];
  const float* bg1  = (const float*)d_in[12];
  const float* root1= (const float*)d_in[13];
  const float* bias1= (const float*)d_in[14];
  const float* emb2 = (const float*)d_in[15];
  const float* wh2  = (const float*)d_in[16];
  const float* bh2  = (const float*)d_in[17];
  const float* wg2  = (const float*)d_in[18];
  const float* bg2  = (const float*)d_in[19];
  const float* root2= (const float*)d_in[20];
  const float* bias2= (const float*)d_in[21];
  const float* emb3 = (const float*)d_in[22];
  const float* wh3  = (const float*)d_in[23];
  const float* bh3  = (const float*)d_in[24];
  const float* wg3  = (const float*)d_in[25];
  const float* bg3  = (const float*)d_in[26];
  const float* root3= (const float*)d_in[27];
  const float* bias3= (const float*)d_in[28];

  const int N = in_sizes[0] / IN1;
  const int E = in_sizes[2];
  const int B = out_size / OUT3;

  // workspace layout (16B-aligned sections)
  int4* edges   = (int4*)d_ws;                       // E recs (16B each)
  int*  deg     = (int*)(edges + E);                 // N
  int*  pos     = deg + N;                           // E
  int*  row_ptr = pos + E;                           // N+1
  int*  bsum    = row_ptr + (N + 1);                 // <=64 chunk sums
  uintptr_t pp  = ((uintptr_t)(bsum + 64) + 15) & ~(uintptr_t)15;
  float4* P1    = (float4*)pp;                       // 25*D1
  float4* P2    = P1 + NTYPES * D1;                  // 25*D2
  float4* P3    = P2 + NTYPES * D2;                  // 25*D3
  float* h1     = (float*)(P3 + NTYPES * D3);        // N*HSTR (48B rows)
  float* h2     = h1 + (size_t)N * HSTR;             // N*HSTR
  float* psum   = h2 + (size_t)N * HSTR;             // B*16
  float* pcnt   = psum + (size_t)B * 16;             // B

  const int nChunk = (N + 1023) / 1024;              // 1024 deg entries per chunk
  const int nPrep  = NTYPES * (D1 + D2 + D3);        // 10500

  zero2_kernel<<<128, 256, 0, stream>>>(deg, N, (int*)psum, B * 16 + B);
  prep_kernel<<<(nPrep + 255) / 256, 256, 0, stream>>>(
      emb1, wh1, bh1, wg1, bg1, emb2, wh2, bh2, wg2, bg2,
      emb3, wh3, bh3, wg3, bg3, P1, P2, P3);
  hist_kernel<<<(E + 255) / 256, 256, 0, stream>>>(edst, deg, pos, E);
  scan_part_kernel<<<nChunk, 256, 0, stream>>>(deg, row_ptr, bsum, N);
  scan_bsum_kernel<<<1, 64, 0, stream>>>(bsum, row_ptr, nChunk, N);
  scan_add_kernel<<<(N + 255) / 256, 256, 0, stream>>>(row_ptr, bsum, N);
  permute_kernel<<<(E + 255) / 256, 256, 0, stream>>>(
      edst, esrc, et, (const float2*)ef, row_ptr, pos, edges, E);

  const int g512 = (N + 31) / 32;     // 32 nodes per 512-thread block
  layer_kernel<IN1, HIDC, IN1, false, 512><<<g512, 512, 0, stream>>>(
      x, edges, row_ptr, P1, root1, bias1,
      h1, nullptr, nullptr, nullptr, N, B);
  layer_kernel<HIDC, HIDC, HSTR, false, 512><<<g512, 512, 0, stream>>>(
      h1, edges, row_ptr, P2, root2, bias2,
      h2, nullptr, nullptr, nullptr, N, B);

  const int g1024 = (N + 63) / 64;    // 64 nodes per 1024-thread block
  layer_kernel<HIDC, OUT3, HSTR, true, 1024><<<g1024, 1024, 0, stream>>>(
      h2, edges, row_ptr, P3, root3, bias3,
      psum, ctype, bids, pcnt, N, B);

  finalize_kernel<<<1, 256, 0, stream>>>(psum, pcnt, (float*)d_out, B);
}